// Round 9
// baseline (156.584 us; speedup 1.0000x reference)
//
#include <hip/hip_runtime.h>

using fx4 = __attribute__((ext_vector_type(4))) float;
using ux2 = __attribute__((ext_vector_type(2))) unsigned int;

__device__ __forceinline__ float bf_lo(unsigned int u) {
    return __uint_as_float(u << 16);
}
__device__ __forceinline__ float bf_hi(unsigned int u) {
    return __uint_as_float(u & 0xffff0000u);
}

// H_bf16 = round_bf16(relu(vfeat @ W + b)), vfeat:[n,64], W:[64,64], b:[64]
__global__ __launch_bounds__(256) void lin_relu_kernel(
    const float* __restrict__ vfeat, const float* __restrict__ W,
    const float* __restrict__ b, unsigned short* __restrict__ Hb, int n_nodes)
{
    __shared__ float sv[8][64];

    const int tid = threadIdx.x;     // 256
    const int c   = tid & 63;        // output column (lane)
    const int w   = tid >> 6;        // wave 0..3

    float wreg[64];
    #pragma unroll
    for (int k = 0; k < 64; ++k) wreg[k] = W[k * 64 + c];
    const float bc = b[c];

    const int ntiles = (n_nodes + 7) >> 3;
    for (int tile = blockIdx.x; tile < ntiles; tile += gridDim.x) {
        const int rbase = tile * 8;
        __syncthreads();             // protect sv from previous-iter readers
        {
            const int i0 = tid, i1 = tid + 256;
            const int r0 = rbase + (i0 >> 6);
            const int r1 = rbase + (i1 >> 6);
            if (r0 < n_nodes) sv[i0 >> 6][i0 & 63] = vfeat[r0 * 64 + (i0 & 63)];
            if (r1 < n_nodes) sv[i1 >> 6][i1 & 63] = vfeat[r1 * 64 + (i1 & 63)];
        }
        __syncthreads();
        #pragma unroll
        for (int rr = 0; rr < 2; ++rr) {
            const int rsub = w * 2 + rr;
            const int r    = rbase + rsub;
            if (r < n_nodes) {
                float acc = bc;
                const fx4* svp = (const fx4*)sv[rsub];   // broadcast ds_read_b128
                #pragma unroll
                for (int k4 = 0; k4 < 16; ++k4) {
                    const fx4 v = svp[k4];
                    acc = fmaf(v.x, wreg[k4 * 4 + 0], acc);
                    acc = fmaf(v.y, wreg[k4 * 4 + 1], acc);
                    acc = fmaf(v.z, wreg[k4 * 4 + 2], acc);
                    acc = fmaf(v.w, wreg[k4 * 4 + 3], acc);
                }
                acc = fmaxf(acc, 0.0f);
                // f32 -> bf16 round-to-nearest-even (finite, >=0)
                const unsigned int u = __float_as_uint(acc);
                Hb[r * 64 + c] = (unsigned short)((u + 0x7fffu + ((u >> 16) & 1u)) >> 16);
            }
        }
    }
}

// out[2][E][64] f32 : out[0][e] = H[src[e]], out[1][e] = H[dst[e]]
// Cache-policy cell 3 of the 2x2: REGULAR stores (L2 write-combining, the
// path the 6.9 TB/s fill uses) + NONTEMPORAL H loads (reads don't allocate
// in L2 -> no read/write L2 contention; H served by L3, latency hidden by
// the 16-deep independent load phase).
__global__ __launch_bounds__(256) void gather_kernel(
    const ux2* __restrict__ H, const int* __restrict__ src,
    const int* __restrict__ dst, fx4* __restrict__ out, int E)
{
    __shared__ int soff[256];                       // node*16 element offsets
    const int tid = threadIdx.x;
    const unsigned base  = (unsigned)blockIdx.x * 4096u;   // first task
    const unsigned total = (unsigned)E * 32u;               // 2*E*16 tasks

    // Phase 1: one row index per thread (coalesced), pre-scaled to ux2 units
    {
        const int r = (int)(base >> 4) + tid;
        int v = 0;
        if (r < E)          v = src[r];
        else if (r < 2 * E) v = dst[r - E];
        soff[tid] = v * 16;
    }
    __syncthreads();

    ux2 hv[16];
    if (base + 4096u <= total) {                    // full block (all but last)
        #pragma unroll
        for (int k = 0; k < 16; ++k) {
            const int lt = k * 256 + tid;           // local task 0..4095
            hv[k] = __builtin_nontemporal_load(&H[soff[lt >> 4] + (lt & 15)]);
        }
        #pragma unroll
        for (int k = 0; k < 16; ++k) {
            fx4 v;
            v.x = bf_lo(hv[k].x); v.y = bf_hi(hv[k].x);
            v.z = bf_lo(hv[k].y); v.w = bf_hi(hv[k].y);
            out[base + (unsigned)(k * 256 + tid)] = v;
        }
    } else {                                        // tail block
        #pragma unroll
        for (int k = 0; k < 16; ++k) {
            const int lt = k * 256 + tid;
            if (base + (unsigned)lt < total)
                hv[k] = __builtin_nontemporal_load(&H[soff[lt >> 4] + (lt & 15)]);
        }
        #pragma unroll
        for (int k = 0; k < 16; ++k) {
            const unsigned g = base + (unsigned)(k * 256 + tid);
            if (g < total) {
                fx4 v;
                v.x = bf_lo(hv[k].x); v.y = bf_hi(hv[k].x);
                v.z = bf_lo(hv[k].y); v.w = bf_hi(hv[k].y);
                out[g] = v;
            }
        }
    }
}

extern "C" void kernel_launch(void* const* d_in, const int* in_sizes, int n_in,
                              void* d_out, int out_size, void* d_ws, size_t ws_size,
                              hipStream_t stream) {
    const float* vfeat = (const float*)d_in[0];
    const int*   src   = (const int*)d_in[1];
    const int*   dst   = (const int*)d_in[2];
    const float* W     = (const float*)d_in[3];
    const float* b     = (const float*)d_in[4];
    float* out = (float*)d_out;

    const int n_nodes = in_sizes[0] / 64;   // 50000
    const int E       = in_sizes[1];        // 1000000

    unsigned short* Hb = (unsigned short*)d_ws;   // n_nodes*64*2 = 6.4 MB

    // 1) Hb = bf16(relu(vfeat @ W + b))
    {
        const int ntiles = (n_nodes + 7) >> 3;
        const int grid = ntiles < 1024 ? ntiles : 1024;
        lin_relu_kernel<<<grid, 256, 0, stream>>>(vfeat, W, b, Hb, n_nodes);
    }

    // 2) gather into both output streams (bf16 -> f32 expand)
    {
        const long total = (long)2 * E * 16;
        const int  nblk  = (int)((total + 4095) / 4096);   // 7813 for E=1e6
        gather_kernel<<<nblk, 256, 0, stream>>>((const ux2*)Hb, src, dst,
                                                (fx4*)out, E);
    }
}

// Round 10
// 131.301 us; speedup vs baseline: 1.1926x; 1.1926x over previous
//
#include <hip/hip_runtime.h>

using fx4 = __attribute__((ext_vector_type(4))) float;
using ux2 = __attribute__((ext_vector_type(2))) unsigned int;

__device__ __forceinline__ float bf_lo(unsigned int u) {
    return __uint_as_float(u << 16);
}
__device__ __forceinline__ float bf_hi(unsigned int u) {
    return __uint_as_float(u & 0xffff0000u);
}

// H_bf16 = round_bf16(relu(vfeat @ W + b)), vfeat:[n,64], W:[64,64], b:[64]
// Wave-per-row: row address is wave-uniform -> vfeat row goes through the
// SCALAR path (s_load_dwordx16, constant cache), FMA reads it as the SGPR
// operand. No LDS, no __syncthreads, no staging chain. W col in 64 VGPRs.
__global__ __launch_bounds__(256) void lin_relu_kernel(
    const float* __restrict__ vfeat, const float* __restrict__ W,
    const float* __restrict__ b, unsigned short* __restrict__ Hb, int n_nodes)
{
    const int tid  = threadIdx.x;    // 256 = 4 waves
    const int c    = tid & 63;       // output column (lane)
    const int wave = tid >> 6;       // 0..3

    float wreg[64];
    #pragma unroll
    for (int k = 0; k < 64; ++k) wreg[k] = W[k * 64 + c];
    const float bc = b[c];

    const int wstride = gridDim.x * 4;
    for (int row = blockIdx.x * 4 + wave; row < n_nodes; row += wstride) {
        // rowp is wave-uniform -> scalar loads
        const float* rowp = vfeat + (size_t)row * 64;
        float acc = bc;
        #pragma unroll
        for (int k = 0; k < 64; ++k)
            acc = fmaf(rowp[k], wreg[k], acc);   // v_fma_f32 v, s, v
        acc = fmaxf(acc, 0.0f);
        // f32 -> bf16 round-to-nearest-even (finite, >=0)
        const unsigned int u = __float_as_uint(acc);
        Hb[(size_t)row * 64 + c] =
            (unsigned short)((u + 0x7fffu + ((u >> 16) & 1u)) >> 16);
    }
}

// out[2][E][64] f32 : out[0][e] = H[src[e]], out[1][e] = H[dst[e]]
// R7 winner, byte-identical: LDS idx staging -> 16 independent cached H
// loads -> 16 NONTEMPORAL stores (stream bypasses L2, H stays resident).
__global__ __launch_bounds__(256) void gather_kernel(
    const ux2* __restrict__ H, const int* __restrict__ src,
    const int* __restrict__ dst, fx4* __restrict__ out, int E)
{
    __shared__ int soff[256];                       // node*16 element offsets
    const int tid = threadIdx.x;
    const unsigned base  = (unsigned)blockIdx.x * 4096u;   // first task
    const unsigned total = (unsigned)E * 32u;               // 2*E*16 tasks

    // Phase 1: one row index per thread (coalesced), pre-scaled to ux2 units
    {
        const int r = (int)(base >> 4) + tid;
        int v = 0;
        if (r < E)          v = src[r];
        else if (r < 2 * E) v = dst[r - E];
        soff[tid] = v * 16;
    }
    __syncthreads();

    ux2 hv[16];
    if (base + 4096u <= total) {                    // full block (all but last)
        #pragma unroll
        for (int k = 0; k < 16; ++k) {
            const int lt = k * 256 + tid;           // local task 0..4095
            hv[k] = H[soff[lt >> 4] + (lt & 15)];   // 16-deep independent MLP
        }
        #pragma unroll
        for (int k = 0; k < 16; ++k) {
            fx4 v;
            v.x = bf_lo(hv[k].x); v.y = bf_hi(hv[k].x);
            v.z = bf_lo(hv[k].y); v.w = bf_hi(hv[k].y);
            __builtin_nontemporal_store(v, &out[base + (unsigned)(k * 256 + tid)]);
        }
    } else {                                        // tail block
        #pragma unroll
        for (int k = 0; k < 16; ++k) {
            const int lt = k * 256 + tid;
            if (base + (unsigned)lt < total)
                hv[k] = H[soff[lt >> 4] + (lt & 15)];
        }
        #pragma unroll
        for (int k = 0; k < 16; ++k) {
            const unsigned g = base + (unsigned)(k * 256 + tid);
            if (g < total) {
                fx4 v;
                v.x = bf_lo(hv[k].x); v.y = bf_hi(hv[k].x);
                v.z = bf_lo(hv[k].y); v.w = bf_hi(hv[k].y);
                __builtin_nontemporal_store(v, &out[g]);
            }
        }
    }
}

extern "C" void kernel_launch(void* const* d_in, const int* in_sizes, int n_in,
                              void* d_out, int out_size, void* d_ws, size_t ws_size,
                              hipStream_t stream) {
    const float* vfeat = (const float*)d_in[0];
    const int*   src   = (const int*)d_in[1];
    const int*   dst   = (const int*)d_in[2];
    const float* W     = (const float*)d_in[3];
    const float* b     = (const float*)d_in[4];
    float* out = (float*)d_out;

    const int n_nodes = in_sizes[0] / 64;   // 50000
    const int E       = in_sizes[1];        // 1000000

    unsigned short* Hb = (unsigned short*)d_ws;   // n_nodes*64*2 = 6.4 MB

    // 1) Hb = bf16(relu(vfeat @ W + b))  — wave-per-row scalar-path version
    lin_relu_kernel<<<1024, 256, 0, stream>>>(vfeat, W, b, Hb, n_nodes);

    // 2) gather into both output streams (bf16 -> f32 expand)
    {
        const long total = (long)2 * E * 16;
        const int  nblk  = (int)((total + 4095) / 4096);   // 7813 for E=1e6
        gather_kernel<<<nblk, 256, 0, stream>>>((const ux2*)Hb, src, dst,
                                                (fx4*)out, E);
    }
}

// Round 11
// 115.857 us; speedup vs baseline: 1.3515x; 1.1333x over previous
//
#include <hip/hip_runtime.h>

using fx4 = __attribute__((ext_vector_type(4))) float;
using ux2 = __attribute__((ext_vector_type(2))) unsigned int;

__device__ __forceinline__ float bf_lo(unsigned int u) {
    return __uint_as_float(u << 16);
}
__device__ __forceinline__ float bf_hi(unsigned int u) {
    return __uint_as_float(u & 0xffff0000u);
}

// H_bf16 = round_bf16(relu(vfeat @ W + b)), vfeat:[n,64], W:[64,64], b:[64]
// R7 winner: LDS row staging + W column in 64 VGPRs, broadcast ds_read_b128.
__global__ __launch_bounds__(256) void lin_relu_kernel(
    const float* __restrict__ vfeat, const float* __restrict__ W,
    const float* __restrict__ b, unsigned short* __restrict__ Hb, int n_nodes)
{
    __shared__ float sv[8][64];

    const int tid = threadIdx.x;     // 256
    const int c   = tid & 63;        // output column (lane)
    const int w   = tid >> 6;        // wave 0..3

    float wreg[64];
    #pragma unroll
    for (int k = 0; k < 64; ++k) wreg[k] = W[k * 64 + c];
    const float bc = b[c];

    const int ntiles = (n_nodes + 7) >> 3;
    for (int tile = blockIdx.x; tile < ntiles; tile += gridDim.x) {
        const int rbase = tile * 8;
        __syncthreads();             // protect sv from previous-iter readers
        {
            const int i0 = tid, i1 = tid + 256;
            const int r0 = rbase + (i0 >> 6);
            const int r1 = rbase + (i1 >> 6);
            if (r0 < n_nodes) sv[i0 >> 6][i0 & 63] = vfeat[r0 * 64 + (i0 & 63)];
            if (r1 < n_nodes) sv[i1 >> 6][i1 & 63] = vfeat[r1 * 64 + (i1 & 63)];
        }
        __syncthreads();
        #pragma unroll
        for (int rr = 0; rr < 2; ++rr) {
            const int rsub = w * 2 + rr;
            const int r    = rbase + rsub;
            if (r < n_nodes) {
                float acc = bc;
                const fx4* svp = (const fx4*)sv[rsub];   // broadcast ds_read_b128
                #pragma unroll
                for (int k4 = 0; k4 < 16; ++k4) {
                    const fx4 v = svp[k4];
                    acc = fmaf(v.x, wreg[k4 * 4 + 0], acc);
                    acc = fmaf(v.y, wreg[k4 * 4 + 1], acc);
                    acc = fmaf(v.z, wreg[k4 * 4 + 2], acc);
                    acc = fmaf(v.w, wreg[k4 * 4 + 3], acc);
                }
                acc = fmaxf(acc, 0.0f);
                // f32 -> bf16 round-to-nearest-even (finite, >=0)
                const unsigned int u = __float_as_uint(acc);
                Hb[r * 64 + c] = (unsigned short)((u + 0x7fffu + ((u >> 16) & 1u)) >> 16);
            }
        }
    }
}

// out[2][E][64] f32 : out[0][e] = H[src[e]], out[1][e] = H[dst[e]]
// Block owns 4096 fx4-tasks (= 256 output rows). Phase 1: stage 256 pre-scaled
// node offsets in LDS. Phase 2: 16 independent cached H loads/thread.
// Phase 3: 16 NONTEMPORAL stores (stream bypasses L2, H stays resident).
__global__ __launch_bounds__(256) void gather_kernel(
    const ux2* __restrict__ H, const int* __restrict__ src,
    const int* __restrict__ dst, fx4* __restrict__ out, int E)
{
    __shared__ int soff[256];                       // node*16 element offsets
    const int tid = threadIdx.x;
    const unsigned base  = (unsigned)blockIdx.x * 4096u;   // first task
    const unsigned total = (unsigned)E * 32u;               // 2*E*16 tasks

    // Phase 1: one row index per thread (coalesced), pre-scaled to ux2 units
    {
        const int r = (int)(base >> 4) + tid;
        int v = 0;
        if (r < E)          v = src[r];
        else if (r < 2 * E) v = dst[r - E];
        soff[tid] = v * 16;
    }
    __syncthreads();

    ux2 hv[16];
    if (base + 4096u <= total) {                    // full block (all but last)
        #pragma unroll
        for (int k = 0; k < 16; ++k) {
            const int lt = k * 256 + tid;           // local task 0..4095
            hv[k] = H[soff[lt >> 4] + (lt & 15)];   // 16-deep independent MLP
        }
        #pragma unroll
        for (int k = 0; k < 16; ++k) {
            fx4 v;
            v.x = bf_lo(hv[k].x); v.y = bf_hi(hv[k].x);
            v.z = bf_lo(hv[k].y); v.w = bf_hi(hv[k].y);
            __builtin_nontemporal_store(v, &out[base + (unsigned)(k * 256 + tid)]);
        }
    } else {                                        // tail block
        #pragma unroll
        for (int k = 0; k < 16; ++k) {
            const int lt = k * 256 + tid;
            if (base + (unsigned)lt < total)
                hv[k] = H[soff[lt >> 4] + (lt & 15)];
        }
        #pragma unroll
        for (int k = 0; k < 16; ++k) {
            const unsigned g = base + (unsigned)(k * 256 + tid);
            if (g < total) {
                fx4 v;
                v.x = bf_lo(hv[k].x); v.y = bf_hi(hv[k].x);
                v.z = bf_lo(hv[k].y); v.w = bf_hi(hv[k].y);
                __builtin_nontemporal_store(v, &out[g]);
            }
        }
    }
}

extern "C" void kernel_launch(void* const* d_in, const int* in_sizes, int n_in,
                              void* d_out, int out_size, void* d_ws, size_t ws_size,
                              hipStream_t stream) {
    const float* vfeat = (const float*)d_in[0];
    const int*   src   = (const int*)d_in[1];
    const int*   dst   = (const int*)d_in[2];
    const float* W     = (const float*)d_in[3];
    const float* b     = (const float*)d_in[4];
    float* out = (float*)d_out;

    const int n_nodes = in_sizes[0] / 64;   // 50000
    const int E       = in_sizes[1];        // 1000000

    unsigned short* Hb = (unsigned short*)d_ws;   // n_nodes*64*2 = 6.4 MB

    // 1) Hb = bf16(relu(vfeat @ W + b))
    {
        const int ntiles = (n_nodes + 7) >> 3;
        const int grid = ntiles < 1024 ? ntiles : 1024;
        lin_relu_kernel<<<grid, 256, 0, stream>>>(vfeat, W, b, Hb, n_nodes);
    }

    // 2) gather into both output streams (bf16 -> f32 expand)
    {
        const long total = (long)2 * E * 16;
        const int  nblk  = (int)((total + 4095) / 4096);   // 7813 for E=1e6
        gather_kernel<<<nblk, 256, 0, stream>>>((const ux2*)Hb, src, dst,
                                                (fx4*)out, E);
    }
}